// Round 2
// baseline (622.577 us; speedup 1.0000x reference)
//
#include <hip/hip_runtime.h>

#define BB 256
#define DD 128
#define KK 4096
#define KT 4097           // K + 1
#define NDATA 500000
#define NM 64000000LL     // NDATA * DD elements of new_memory

__device__ __forceinline__ float wave_sum_f(float v) {
#pragma unroll
    for (int o = 32; o; o >>= 1) v += __shfl_xor(v, o);
    return v;
}
__device__ __forceinline__ double wave_sum_d(double v) {
#pragma unroll
    for (int o = 32; o; o >>= 1) v += __shfl_xor(v, o);
    return v;
}

// ---------------------------------------------------------------------------
// 1) row-wise l2norm of f_s; w_pos = l2norm(0.5*memory[idx[b]] + 0.5*l2norm(f_t))
//    grid: 256 blocks x 128 threads (one block per b)
// ---------------------------------------------------------------------------
__global__ void norm_kernel(const float* __restrict__ fs, const float* __restrict__ ft,
                            const float* __restrict__ mem, const int* __restrict__ idx,
                            float* __restrict__ fs_n, float* __restrict__ wpos) {
    __shared__ float lds[2];
    const int b = blockIdx.x, d = threadIdx.x;
    const int lane = d & 63, wv = d >> 6;

    float vs = fs[b * DD + d];
    float s = wave_sum_f(vs * vs);
    if (lane == 0) lds[wv] = s;
    __syncthreads();
    float tot = lds[0] + lds[1];
    fs_n[b * DD + d] = vs / sqrtf(tot);
    __syncthreads();

    float vt = ft[b * DD + d];
    s = wave_sum_f(vt * vt);
    if (lane == 0) lds[wv] = s;
    __syncthreads();
    tot = lds[0] + lds[1];
    float ftn = vt / sqrtf(tot);
    __syncthreads();

    float w = mem[(size_t)idx[b] * DD + d] * 0.5f + ftn * 0.5f;
    s = wave_sum_f(w * w);
    if (lane == 0) lds[wv] = s;
    __syncthreads();
    tot = lds[0] + lds[1];
    wpos[b * DD + d] = w / sqrtf(tot);
}

// ---------------------------------------------------------------------------
// 2) out[b,k] = exp(dot(memory[all_idx[b,k]], fs_n[b]) / 0.07)  (stored f32;
//    representable since |dot| <~ 6.5 -> e^{+-93} is within f32 range for the
//    values that actually occur). Per-block f64 partial of sum(out).
// ---------------------------------------------------------------------------
__global__ __launch_bounds__(256) void dot_kernel(
    const float* __restrict__ mem, const int* __restrict__ idx,
    const int* __restrict__ cidx, const float* __restrict__ fs_n,
    float* __restrict__ outb, double* __restrict__ zpart) {
    const int KCH = 257;  // ceil(4097/16)
    const int b = blockIdx.x >> 4;
    const int ch = blockIdx.x & 15;
    const int lane = threadIdx.x & 63;
    const int wv = threadIdx.x >> 6;

    const float2 f = ((const float2*)(fs_n + b * DD))[lane];
    const int k0 = ch * KCH;
    const int k1 = min(KT, k0 + KCH);

    double local = 0.0;
    for (int k = k0 + wv; k < k1; k += 4) {
        int row = (k == 0) ? idx[b] : cidx[b * KK + (k - 1)];
        float2 m = ((const float2*)(mem + (size_t)row * DD))[lane];
        float dsum = wave_sum_f(f.x * m.x + f.y * m.y);
        if (lane == 0) {
            float e = expf(dsum / 0.07f);
            outb[b * KT + k] = e;
            local += (double)e;
        }
    }
    __shared__ double sds[4];
    if (lane == 0) sds[wv] = local;
    __syncthreads();
    if (threadIdx.x == 0) zpart[blockIdx.x] = (sds[0] + sds[1]) + (sds[2] + sds[3]);
}

// ---------------------------------------------------------------------------
// 3) Z = mean(out) * N_DATA, kept in f64 so out/Z does not underflow later
// ---------------------------------------------------------------------------
__global__ void reduce_z_kernel(const double* __restrict__ zpart, double* __restrict__ Zval) {
    double s = 0.0;
    for (int i = threadIdx.x; i < 4096; i += 256) s += zpart[i];
    s = wave_sum_d(s);
    __shared__ double lds[4];
    const int lane = threadIdx.x & 63, wv = threadIdx.x >> 6;
    if (lane == 0) lds[wv] = s;
    __syncthreads();
    if (threadIdx.x == 0) {
        double tot = (lds[0] + lds[1]) + (lds[2] + lds[3]);
        *Zval = (tot / (double)(BB * KT)) * 500000.0;
    }
}

// ---------------------------------------------------------------------------
// 4) per-block f64 partials of sum(log_D1) + sum(log_D0). All in f64 so the
//    positive-sample val ~ 1e-60 stays representable and logs stay finite.
// ---------------------------------------------------------------------------
__global__ __launch_bounds__(256) void loss_kernel(const float* __restrict__ outb,
                                                   const double* __restrict__ Zval,
                                                   double* __restrict__ lpart) {
    const double MPN = 4096.0 / 500000.0;  // m * Pn
    const double Z = *Zval;
    const int TOT = BB * KT;
    double s = 0.0;
    for (int e = blockIdx.x * blockDim.x + threadIdx.x; e < TOT;
         e += gridDim.x * blockDim.x) {
        int k = e % KT;
        double val = (double)outb[e] / Z;
        double den = (val + MPN) + 1e-7;
        double num = (k == 0) ? val : MPN;
        s += log(num / den);
    }
    s = wave_sum_d(s);
    __shared__ double lds[4];
    const int lane = threadIdx.x & 63, wv = threadIdx.x >> 6;
    if (lane == 0) lds[wv] = s;
    __syncthreads();
    if (threadIdx.x == 0) lpart[blockIdx.x] = (lds[0] + lds[1]) + (lds[2] + lds[3]);
}

// ---------------------------------------------------------------------------
// 5) loss = -(sum / B) / P
// ---------------------------------------------------------------------------
__global__ void finalize_kernel(const double* __restrict__ lpart, float* __restrict__ dout) {
    double s = 0.0;
    for (int i = threadIdx.x; i < 1024; i += 256) s += lpart[i];
    s = wave_sum_d(s);
    __shared__ double lds[4];
    const int lane = threadIdx.x & 63, wv = threadIdx.x >> 6;
    if (lane == 0) lds[wv] = s;
    __syncthreads();
    if (threadIdx.x == 0) {
        double tot = (lds[0] + lds[1]) + (lds[2] + lds[3]);
        dout[0] = (float)(-(tot / 256.0));
    }
}

// ---------------------------------------------------------------------------
// 6) new_memory bulk copy: dst[1+e] = src[e]. dst is off-by-one-float, so load
//    aligned float4, shift one lane via shfl_up, store aligned float4.
// ---------------------------------------------------------------------------
__global__ __launch_bounds__(256) void copy_kernel(const float* __restrict__ src,
                                                   float* __restrict__ dst) {
    const long long NJ = NM / 4;  // float4 groups; j in [1, NJ)
    long long tid = (long long)blockIdx.x * blockDim.x + threadIdx.x;
    long long stride = (long long)gridDim.x * blockDim.x;
    for (long long j = 1 + tid; j < NJ; j += stride) {
        float4 v = ((const float4*)src)[j];
        float pv = __shfl_up(v.w, 1);
        if ((threadIdx.x & 63) == 0) pv = src[4 * j - 1];
        float4 o;
        o.x = pv; o.y = v.x; o.z = v.y; o.w = v.z;
        ((float4*)dst)[j] = o;  // dst dwords [4j, 4j+4) = elements [4j-1, 4j+3)
    }
    if (blockIdx.x == 0 && threadIdx.x == 0) {
        dst[1] = src[0]; dst[2] = src[1]; dst[3] = src[2];
        dst[NM] = src[NM - 1];
    }
}

// ---------------------------------------------------------------------------
// 7) scatter updated rows (last duplicate wins, like sequential .at[].set)
// ---------------------------------------------------------------------------
__global__ void scatter_kernel(const int* __restrict__ idx, const float* __restrict__ wpos,
                               float* __restrict__ dst) {
    const int b = blockIdx.x, d = threadIdx.x;
    const int row = idx[b];
    bool write = true;
    for (int b2 = b + 1; b2 < BB; ++b2)
        if (idx[b2] == row) { write = false; break; }
    if (write) dst[1 + (size_t)row * DD + d] = wpos[b * DD + d];
}

extern "C" void kernel_launch(void* const* d_in, const int* in_sizes, int n_in,
                              void* d_out, int out_size, void* d_ws, size_t ws_size,
                              hipStream_t stream) {
    const float* fs = (const float*)d_in[0];
    const float* ft = (const float*)d_in[1];
    const float* mem = (const float*)d_in[2];
    const int* idx = (const int*)d_in[3];
    const int* cidx = (const int*)d_in[4];
    float* out_f = (float*)d_out;

    char* ws = (char*)d_ws;
    double* zpart = (double*)ws;               // 4096 * 8  = 32768 B
    double* lpart = (double*)(ws + 32768);     // 1024 * 8  =  8192 B
    double* Zval  = (double*)(ws + 40960);     //             8 B (8-aligned)
    float* fs_n   = (float*)(ws + 41024);      // 32768 * 4 = 131072 B
    float* wpos   = (float*)(ws + 41024 + 131072);  // 131072 B
    float* outb   = out_f + 1;  // 4.2 MB scratch inside d_out; overwritten by copy later

    norm_kernel<<<256, 128, 0, stream>>>(fs, ft, mem, idx, fs_n, wpos);
    dot_kernel<<<4096, 256, 0, stream>>>(mem, idx, cidx, fs_n, outb, zpart);
    reduce_z_kernel<<<1, 256, 0, stream>>>(zpart, Zval);
    loss_kernel<<<1024, 256, 0, stream>>>(outb, Zval, lpart);
    finalize_kernel<<<1, 256, 0, stream>>>(lpart, out_f);
    copy_kernel<<<2048, 256, 0, stream>>>(mem, out_f);
    scatter_kernel<<<256, 128, 0, stream>>>(idx, wpos, out_f);
}